// Round 8
// baseline (156.552 us; speedup 1.0000x reference)
//
#include <hip/hip_runtime.h>

#define BB 8
#define C 64
#define HW 4096

typedef __attribute__((ext_vector_type(8))) __bf16 bf16x8;
typedef __attribute__((ext_vector_type(16))) float f32x16;
typedef unsigned int uint;
typedef unsigned short ushort;

__device__ __forceinline__ ushort bfb(float f) {
  return __builtin_bit_cast(ushort, (__bf16)f);
}
__device__ __forceinline__ uint pk2(float a, float b) {
  return (uint)bfb(a) | ((uint)bfb(b) << 16);
}
__device__ __forceinline__ uint cvtpk(float a, float b) {
  uint r;
  asm("v_cvt_pk_bf16_f32 %0, %1, %2" : "=v"(r) : "v"(a), "v"(b));
  return r;
}
__device__ __forceinline__ void gload_lds16(const void* g, void* l) {
  __builtin_amdgcn_global_load_lds((const __attribute__((address_space(1))) void*)g,
                                   (__attribute__((address_space(3))) void*)l, 16, 0, 0);
}
__device__ __forceinline__ f32x16 mfma_bf16(bf16x8 a, bf16x8 b, f32x16 c) {
  return __builtin_amdgcn_mfma_f32_32x32x16_bf16(a, b, c, 0, 0, 0);
}

// ---------------- fold: build wall A/B fragments for {q*log2e, k, wvp} ----------------
__global__ __launch_bounds__(64) void fold_kernel(const float* __restrict__ w_bn,
                                                  const float* __restrict__ w_q,
                                                  const float* __restrict__ w_k,
                                                  const float* __restrict__ w_v,
                                                  char* __restrict__ wall) {
  const int slot = blockIdx.x;         // ot*4 + kc
  const int ot = slot >> 2, kc = slot & 3;
  const int l = threadIdx.x, lo5 = l & 31, hi = l >> 5;
  float v[8];
  if (ot == 0) {
#pragma unroll
    for (int j = 0; j < 8; ++j)
      v[j] = 1.44269504088896f * w_q[lo5 * 64 + kc * 16 + hi * 8 + j];
  } else if (ot == 1) {
#pragma unroll
    for (int j = 0; j < 8; ++j) v[j] = w_k[lo5 * 64 + kc * 16 + hi * 8 + j];
  } else {
    int c = (ot - 2) * 32 + lo5;
#pragma unroll
    for (int j = 0; j < 8; ++j) {
      int d = kc * 16 + hi * 8 + j;
      float acc = 0.f;
      for (int e = 0; e < 64; ++e) acc += w_bn[c * 128 + 64 + e] * w_v[e * 64 + d];
      v[j] = acc;
    }
  }
  uint4 w;
  w.x = pk2(v[0], v[1]); w.y = pk2(v[2], v[3]);
  w.z = pk2(v[4], v[5]); w.w = pk2(v[6], v[7]);
  *(uint4*)(wall + slot * 1024 + l * 16) = w;
}

// ---------------- prep: q/k/vp via MFMA, outputs in exact fa fragment layouts ----------------
__global__ __launch_bounds__(128) void prep_kernel(const float* __restrict__ x,
                                                   const char* __restrict__ wall,
                                                   char* __restrict__ qd2,
                                                   char* __restrict__ kd2,
                                                   char* __restrict__ vpd2) {
  const int bx = blockIdx.x;
  const int b = bx >> 6, nt = bx & 63;
  const int t = threadIdx.x;
  const int wv = t >> 6, l = t & 63, lo5 = l & 31, hi = l >> 5;
  const int n0 = nt * 64 + wv * 32;
  const int tt = nt;
  const int n = n0 + lo5;
  const float* xb = x + (size_t)b * C * HW;

  f32x16 fz;
#pragma unroll
  for (int r = 0; r < 16; ++r) fz[r] = 0.f;

  bf16x8 xf[4];
#pragma unroll
  for (int kc = 0; kc < 4; ++kc) {
    float xv[8];
#pragma unroll
    for (int j = 0; j < 8; ++j)
      xv[j] = xb[(size_t)(kc * 16 + hi * 8 + j) * HW + n];
    uint4 u;
    u.x = cvtpk(xv[0], xv[1]); u.y = cvtpk(xv[2], xv[3]);
    u.z = cvtpk(xv[4], xv[5]); u.w = cvtpk(xv[6], xv[7]);
    xf[kc] = __builtin_bit_cast(bf16x8, u);
  }

#pragma unroll
  for (int ot = 0; ot < 4; ++ot) {
    f32x16 acc = fz;
#pragma unroll
    for (int kc = 0; kc < 4; ++kc) {
      bf16x8 wf = *(const bf16x8*)(wall + ((ot << 2) | kc) * 1024 + l * 16);
      acc = (ot < 2) ? mfma_bf16(wf, xf[kc], acc)    // D[col=n][row=out]
                     : mfma_bf16(xf[kc], wf, acc);   // D[col=c][row=m]
    }
    // extract pairs: wlo = pair from hi=0 lane (row offset +0), whi = from hi=1 (+4)
    uint wlo[8], whi[8];
#pragma unroll
    for (int i2 = 0; i2 < 8; ++i2) {
      uint w = cvtpk(acc[2 * i2], acc[2 * i2 + 1]);
      uint p = __shfl_xor(w, 32);
      wlo[i2] = hi ? p : w;
      whi[i2] = hi ? w : p;
    }
    uint4 u40, u41;
    u40.x = hi ? wlo[4] : wlo[0];
    u40.y = hi ? wlo[5] : wlo[1];
    u40.z = hi ? whi[4] : whi[0];
    u40.w = hi ? whi[5] : whi[1];
    u41.x = hi ? wlo[6] : wlo[2];
    u41.y = hi ? wlo[7] : wlo[3];
    u41.z = hi ? whi[6] : whi[2];
    u41.w = hi ? whi[7] : whi[3];
    const int e0 = hi * 2;
    if (ot == 0) {
      char* p = qd2 + ((size_t)b * HW + n) * 64;
      *(uint4*)(p + e0 * 16) = u40;
      *(uint4*)(p + (e0 + 1) * 16) = u41;
    } else if (ot == 1) {
      char* p = kd2 + ((size_t)(b * 64 + tt)) * 4096 + ((n & 63) >> 5) * 2048 + (n & 31) * 16;
      *(uint4*)(p + e0 * 512) = u40;
      *(uint4*)(p + (e0 + 1) * 512) = u41;
    } else {
      int c = ((ot - 2) << 5) + lo5;
      int oct0 = wv * 4;
      char* p = vpd2 + ((size_t)(b * 64 + tt)) * 8192 + (c >> 5) * 4096 + (c & 31) * 16;
      *(uint4*)(p + (oct0 + e0) * 512) = u40;
      *(uint4*)(p + (oct0 + e0 + 1) * 512) = u41;
    }
  }
}

// ---------------- gram: per-wave partial G = X X^T, split-x (h+l) bf16 MFMA ----------------
__global__ __launch_bounds__(128) void gram_kernel(const float* __restrict__ x,
                                                   float* __restrict__ Gp) {
  const int bx = blockIdx.x;
  const int b = bx >> 4, ch = bx & 15;
  const int t = threadIdx.x;
  const int wv = t >> 6, l = t & 63, lo5 = l & 31, hi = l >> 5;
  const int n0 = ch * 256 + wv * 128;
  const float* xb = x + (size_t)b * C * HW;
  f32x16 fz;
#pragma unroll
  for (int r = 0; r < 16; ++r) fz[r] = 0.f;
  f32x16 a00 = fz, a01 = fz, a10 = fz, a11 = fz;
#pragma unroll 1
  for (int kc = 0; kc < 8; ++kc) {
    int nb = n0 + kc * 16 + hi * 8;
    const float4* p0 = (const float4*)(xb + (size_t)lo5 * HW + nb);
    const float4* p1 = (const float4*)(xb + (size_t)(32 + lo5) * HW + nb);
    float v0[8], v1[8];
    {
      float4 a = p0[0], bq = p0[1];
      v0[0] = a.x; v0[1] = a.y; v0[2] = a.z; v0[3] = a.w;
      v0[4] = bq.x; v0[5] = bq.y; v0[6] = bq.z; v0[7] = bq.w;
      float4 c = p1[0], d = p1[1];
      v1[0] = c.x; v1[1] = c.y; v1[2] = c.z; v1[3] = c.w;
      v1[4] = d.x; v1[5] = d.y; v1[6] = d.z; v1[7] = d.w;
    }
    uint4 uh0, ul0, uh1, ul1;
    {
      float h[8], e[8];
#pragma unroll
      for (int j = 0; j < 8; ++j) { h[j] = (float)(__bf16)v0[j]; e[j] = v0[j] - h[j]; }
      uh0.x = pk2(h[0], h[1]); uh0.y = pk2(h[2], h[3]); uh0.z = pk2(h[4], h[5]); uh0.w = pk2(h[6], h[7]);
      ul0.x = cvtpk(e[0], e[1]); ul0.y = cvtpk(e[2], e[3]); ul0.z = cvtpk(e[4], e[5]); ul0.w = cvtpk(e[6], e[7]);
#pragma unroll
      for (int j = 0; j < 8; ++j) { h[j] = (float)(__bf16)v1[j]; e[j] = v1[j] - h[j]; }
      uh1.x = pk2(h[0], h[1]); uh1.y = pk2(h[2], h[3]); uh1.z = pk2(h[4], h[5]); uh1.w = pk2(h[6], h[7]);
      ul1.x = cvtpk(e[0], e[1]); ul1.y = cvtpk(e[2], e[3]); ul1.z = cvtpk(e[4], e[5]); ul1.w = cvtpk(e[6], e[7]);
    }
    bf16x8 f0h = __builtin_bit_cast(bf16x8, uh0);
    bf16x8 f0l = __builtin_bit_cast(bf16x8, ul0);
    bf16x8 f1h = __builtin_bit_cast(bf16x8, uh1);
    bf16x8 f1l = __builtin_bit_cast(bf16x8, ul1);
    a00 = mfma_bf16(f0h, f0h, a00); a00 = mfma_bf16(f0h, f0l, a00); a00 = mfma_bf16(f0l, f0h, a00);
    a01 = mfma_bf16(f0h, f1h, a01); a01 = mfma_bf16(f0h, f1l, a01); a01 = mfma_bf16(f0l, f1h, a01);
    a10 = mfma_bf16(f1h, f0h, a10); a10 = mfma_bf16(f1h, f0l, a10); a10 = mfma_bf16(f1l, f0h, a10);
    a11 = mfma_bf16(f1h, f1h, a11); a11 = mfma_bf16(f1h, f1l, a11); a11 = mfma_bf16(f1l, f1h, a11);
  }
  float* g = Gp + (size_t)(bx * 2 + wv) * 4096;
#pragma unroll
  for (int r = 0; r < 16; ++r) {
    int row = (r & 3) + 8 * (r >> 2) + 4 * hi;
    g[row * 64 + lo5] = a00[r];
    g[row * 64 + 32 + lo5] = a01[r];
    g[(32 + row) * 64 + lo5] = a10[r];
    g[(32 + row) * 64 + 32 + lo5] = a11[r];
  }
}

// ---------------- CAM (1024 threads): reduce G, E = Wc G Wc^T, softmax, M1 ([d][o]) ----------------
__global__ __launch_bounds__(1024) void cam_m1_kernel(const float* __restrict__ Gp,
                                                      const float* __restrict__ w_cam,
                                                      const float* __restrict__ w_bn,
                                                      float* __restrict__ m1) {
  __shared__ float gs[4096];
  __shared__ float ts[4096];
  __shared__ float wcs[4096];
  __shared__ float wts[4096];
  const int b = blockIdx.x, t = threadIdx.x;
#pragma unroll
  for (int i = 0; i < 4; ++i) {
    int idx = t + i * 1024;
    float s = 0.f;
    for (int s32 = 0; s32 < 32; ++s32)
      s += Gp[(size_t)(b * 32 + s32) * 4096 + idx];
    gs[idx] = s;
  }
  ((float4*)wcs)[t] = ((const float4*)w_cam)[t];
  __syncthreads();
#pragma unroll
  for (int i = 0; i < 4; ++i) {
    int idx = t + i * 1024;
    int r = idx >> 6, d = idx & 63;
    wts[d * 64 + r] = wcs[r * 64 + d];
  }
  __syncthreads();
  const int lane = t & 63, rg = (t >> 6) * 4;
  float acc[4] = {0.f, 0.f, 0.f, 0.f};
  for (int c = 0; c < 64; ++c) {
    float g = gs[c * 64 + lane];
#pragma unroll
    for (int r = 0; r < 4; ++r) acc[r] += wcs[(rg + r) * 64 + c] * g;
  }
#pragma unroll
  for (int r = 0; r < 4; ++r) ts[(rg + r) * 64 + lane] = acc[r];
  __syncthreads();
#pragma unroll
  for (int r = 0; r < 4; ++r) acc[r] = 0.f;
  for (int d = 0; d < 64; ++d) {
    float w = wts[d * 64 + lane];
#pragma unroll
    for (int r = 0; r < 4; ++r) acc[r] += ts[(rg + r) * 64 + d] * w;
  }
  __syncthreads();
#pragma unroll
  for (int r = 0; r < 4; ++r) gs[(rg + r) * 64 + lane] = acc[r];
  __syncthreads();
  {
    // softmax: 16 lanes per row, 4 cols each
    int row = t >> 4, c0 = (t & 15) * 4;
    float v0 = gs[row * 64 + c0], v1 = gs[row * 64 + c0 + 1];
    float v2 = gs[row * 64 + c0 + 2], v3 = gs[row * 64 + c0 + 3];
    float mx = fmaxf(fmaxf(v0, v1), fmaxf(v2, v3));
#pragma unroll
    for (int o = 1; o < 16; o <<= 1) mx = fmaxf(mx, __shfl_xor(mx, o));
    float e0 = __expf(v0 - mx), e1 = __expf(v1 - mx);
    float e2 = __expf(v2 - mx), e3 = __expf(v3 - mx);
    float s = e0 + e1 + e2 + e3;
#pragma unroll
    for (int o = 1; o < 16; o <<= 1) s += __shfl_xor(s, o);
    float inv = 1.f / s;
    wcs[row * 64 + c0] = e0 * inv;
    wcs[row * 64 + c0 + 1] = e1 * inv;
    wcs[row * 64 + c0 + 2] = e2 * inv;
    wcs[row * 64 + c0 + 3] = e3 * inv;
  }
#pragma unroll
  for (int i = 0; i < 4; ++i) {
    int idx = t + i * 1024;
    int o = idx & 63, r = idx >> 6;
    wts[r * 64 + o] = w_bn[o * 128 + r];
  }
  __syncthreads();
  float a2[4] = {0.f, 0.f, 0.f, 0.f};
  for (int r = 0; r < 64; ++r) {
    float wv = wts[r * 64 + lane];
#pragma unroll
    for (int dd = 0; dd < 4; ++dd) a2[dd] += wv * wcs[r * 64 + rg + dd];
  }
  float* mb = m1 + (size_t)b * 4096;
#pragma unroll
  for (int dd = 0; dd < 4; ++dd) mb[(rg + dd) * 64 + lane] = a2[dd];
}

// ---------------- SAM flash attention: 3-buffer ring, counted vmcnt, raw barriers ----------------
__global__ __launch_bounds__(256) void fa_kernel(const char* __restrict__ qd2,
                                                 const char* __restrict__ kd2,
                                                 const char* __restrict__ vpd2,
                                                 char* __restrict__ op,
                                                 float* __restrict__ lp) {
  __shared__ __align__(16) char smem[36864];   // 3 x 12 KB ring
  const int t = threadIdx.x;
  const int l = t & 63, lo5 = l & 31, hi = l >> 5;
  const int wv = t >> 6;
  const int bx = blockIdx.x;
  const int g = (bx & 7) | ((bx >> 8) << 3);
  const int qt = (bx >> 3) & 31;
  const int b = g >> 2, kvs = g & 3;
  const int nq = qt * 128 + wv * 32 + lo5;

  const char* qb = qd2 + ((size_t)b * HW + nq) * 64;
  bf16x8 qf0 = *(const bf16x8*)(qb + hi * 16);
  bf16x8 qf1 = *(const bf16x8*)(qb + 32 + hi * 16);

  f32x16 fz;
#pragma unroll
  for (int r = 0; r < 16; ++r) fz[r] = 0.f;
  f32x16 o0 = fz, o1 = fz;
  float lrun = 0.f;

  const size_t kb0 = ((size_t)(b * 64 + kvs * 16)) * 4096;
  const size_t vb0 = ((size_t)(b * 64 + kvs * 16)) * 8192;

  // each wave issues exactly 3 global_load_lds per stage
  auto stage = [&](int it) {
    char* dstb = smem + (it % 3) * 12288;
#pragma unroll
    for (int ss = 0; ss < 3; ++ss) {
      int s = wv * 3 + ss;
      const char* gsrc = (s < 4) ? (kd2 + kb0 + (size_t)it * 4096 + s * 1024)
                                 : (vpd2 + vb0 + (size_t)it * 8192 + (s - 4) * 1024);
      gload_lds16(gsrc + l * 16, dstb + s * 1024);
    }
  };

  auto compute = [&](int i) {
    const char* kb = smem + (i % 3) * 12288;
    const char* vb = kb + 4096;
    bf16x8 kf00 = *(const bf16x8*)(kb + l * 16);
    bf16x8 kf01 = *(const bf16x8*)(kb + 1024 + l * 16);
    bf16x8 kf10 = *(const bf16x8*)(kb + 2048 + l * 16);
    bf16x8 kf11 = *(const bf16x8*)(kb + 3072 + l * 16);
    f32x16 s0 = mfma_bf16(kf00, qf0, fz);
    s0 = mfma_bf16(kf01, qf1, s0);
    f32x16 s1 = mfma_bf16(kf10, qf0, fz);
    s1 = mfma_bf16(kf11, qf1, s1);
    bf16x8 vfa[4], vfb[4];
#pragma unroll
    for (int ks = 0; ks < 4; ++ks) {
      vfa[ks] = *(const bf16x8*)(vb + ks * 1024 + l * 16);
      vfb[ks] = *(const bf16x8*)(vb + 4096 + ks * 1024 + l * 16);
    }
    float ps = 0.f;
#pragma unroll
    for (int r = 0; r < 16; ++r) {
      s0[r] = __builtin_amdgcn_exp2f(s0[r]);
      ps += s0[r];
    }
#pragma unroll
    for (int r = 0; r < 16; ++r) {
      s1[r] = __builtin_amdgcn_exp2f(s1[r]);
      ps += s1[r];
    }
    ps += __shfl_xor(ps, 32);
    lrun += ps;
#pragma unroll
    for (int ks = 0; ks < 4; ++ks) {
      const f32x16& pm = (ks < 2) ? s0 : s1;
      const int rb = (ks & 1) * 8;
      uint w0 = cvtpk(pm[rb + 0], pm[rb + 1]);
      uint w1 = cvtpk(pm[rb + 2], pm[rb + 3]);
      uint w2 = cvtpk(pm[rb + 4], pm[rb + 5]);
      uint w3 = cvtpk(pm[rb + 6], pm[rb + 7]);
      uint x0 = __shfl_xor(w0, 32);
      uint x1 = __shfl_xor(w1, 32);
      uint x2 = __shfl_xor(w2, 32);
      uint x3 = __shfl_xor(w3, 32);
      uint4 fw;
      fw.x = hi ? x2 : w0;
      fw.y = hi ? x3 : w1;
      fw.z = hi ? w2 : x0;
      fw.w = hi ? w3 : x1;
      bf16x8 pf = __builtin_bit_cast(bf16x8, fw);
      o0 = mfma_bf16(vfa[ks], pf, o0);
      o1 = mfma_bf16(vfb[ks], pf, o1);
    }
  };

  stage(0);
  stage(1);

  // ledger: at top of iter i, outstanding = stages {i, i+1} (6 loads/wave).
  // vmcnt(3) certifies tile i's 3 loads done; barrier makes all waves' tile-i
  // writes visible AND certifies compute(i-1) finished block-wide, so
  // stage(i+2) may overwrite buf[(i+2)%3] (last read at compute(i-1)).
#pragma unroll 1
  for (int i = 0; i < 15; ++i) {
    asm volatile("s_waitcnt vmcnt(3)" ::: "memory");
    __builtin_amdgcn_s_barrier();
    asm volatile("" ::: "memory");
    if (i < 14) stage(i + 2);
    compute(i);
  }
  asm volatile("s_waitcnt vmcnt(0)" ::: "memory");
  __builtin_amdgcn_s_barrier();
  asm volatile("" ::: "memory");
  compute(15);

  ushort* opu = (ushort*)op;
  const size_t obase = ((size_t)(b * 64) * 4 + kvs) * HW + nq;
#pragma unroll
  for (int r = 0; r < 16; ++r) {
    int c0 = (r & 3) + 8 * (r >> 2) + 4 * hi;
    opu[obase + (size_t)c0 * 4 * HW] = bfb(o0[r]);
    opu[obase + (size_t)(c0 + 32) * 4 * HW] = bfb(o1[r]);
  }
  if (hi == 0) lp[(size_t)(kvs * 8 + b) * HW + nq] = lrun;
}

// ---------------- epilogue: out = x + M1@x + merge(op)/merge(l) ----------------
__global__ __launch_bounds__(256) void final_kernel(const float* __restrict__ x,
                                                    const float* __restrict__ m1,
                                                    const char* __restrict__ op,
                                                    const float* __restrict__ lp,
                                                    float* __restrict__ outp) {
  __shared__ __align__(16) float xt[4096];
  __shared__ __align__(16) float ms[4096];
  const int b = blockIdx.y, tt = blockIdx.x, t = threadIdx.x;
  const float4* xg = (const float4*)(x + (size_t)b * C * HW);
  float4* xt4 = (float4*)xt;
#pragma unroll
  for (int i = 0; i < 4; ++i) {
    int idx = t + i * 256;
    int c = idx >> 4, ng = idx & 15;
    xt4[c * 16 + (ng ^ (c & 15))] = xg[c * 1024 + tt * 16 + ng];
  }
  float4* ms4 = (float4*)ms;
  const float4* mg = (const float4*)(m1 + (size_t)b * 4096);
#pragma unroll
  for (int i = 0; i < 4; ++i) ms4[t + i * 256] = mg[t + i * 256];
  __syncthreads();
  const int n = t & 63, sub = t >> 6;
  const int gn = tt * 64 + n;
  float xr[64];
#pragma unroll
  for (int c = 0; c < 64; ++c)
    xr[c] = xt[c * 64 + (((n >> 2) ^ (c & 15)) << 2) + (n & 3)];
  float lsum = 0.f;
#pragma unroll
  for (int kvs = 0; kvs < 4; ++kvs) lsum += lp[(size_t)(kvs * 8 + b) * HW + gn];
  float linv = 1.f / lsum;
  const ushort* opu = (const ushort*)op;
  float acc[16];
#pragma unroll
  for (int ci = 0; ci < 16; ++ci) {
    int c = sub * 16 + ci;
    float osum = 0.f;
#pragma unroll
    for (int kvs = 0; kvs < 4; ++kvs) {
      ushort u = opu[((size_t)(b * 64 + c) * 4 + kvs) * HW + gn];
      osum += __builtin_bit_cast(float, (uint)u << 16);
    }
    acc[ci] = xr[c] + osum * linv;
  }
  for (int d = 0; d < 64; ++d) {
    float xv = xr[d];
    const float4* mr = (const float4*)(ms + d * 64 + sub * 16);
#pragma unroll
    for (int c4 = 0; c4 < 4; ++c4) {
      float4 mv = mr[c4];
      acc[c4 * 4 + 0] += mv.x * xv;
      acc[c4 * 4 + 1] += mv.y * xv;
      acc[c4 * 4 + 2] += mv.z * xv;
      acc[c4 * 4 + 3] += mv.w * xv;
    }
  }
  float* ob = outp + (size_t)b * C * HW + gn;
#pragma unroll
  for (int ci = 0; ci < 16; ++ci)
    ob[(size_t)(sub * 16 + ci) * HW] = acc[ci];
}

extern "C" void kernel_launch(void* const* d_in, const int* in_sizes, int n_in,
                              void* d_out, int out_size, void* d_ws, size_t ws_size,
                              hipStream_t stream) {
  const float* x     = (const float*)d_in[0];
  const float* w_cam = (const float*)d_in[1];
  const float* w_q   = (const float*)d_in[2];
  const float* w_k   = (const float*)d_in[3];
  const float* w_v   = (const float*)d_in[4];
  const float* w_bn  = (const float*)d_in[5];
  float* out = (float*)d_out;
  char* wsb = (char*)d_ws;

  // workspace layout (bytes)
  char*  wall = wsb;                               // 16 KB  wall fragments
  float* m1   = (float*)(wsb + 16384);             // 128 KB
  char*  qd2  = wsb + 147456;                      // 2 MB
  char*  kd2  = qd2 + 2097152;                     // 2 MB
  char*  vpd2 = kd2 + 2097152;                     // 4 MB
  float* lp   = (float*)(vpd2 + 4194304);          // 512 KB
  char*  un   = (char*)lp + 524288;                // 16 MB union: Gp (4MB) then op
  float* Gp   = (float*)un;
  char*  op   = un;

  fold_kernel<<<16, 64, 0, stream>>>(w_bn, w_q, w_k, w_v, wall);
  prep_kernel<<<512, 128, 0, stream>>>(x, wall, qd2, kd2, vpd2);
  gram_kernel<<<128, 128, 0, stream>>>(x, Gp);
  cam_m1_kernel<<<8, 1024, 0, stream>>>(Gp, w_cam, w_bn, m1);
  fa_kernel<<<1024, 256, 0, stream>>>(qd2, kd2, vpd2, op, lp);
  final_kernel<<<dim3(64, BB), 256, 0, stream>>>(x, m1, op, lp, out);
}

// Round 9
// 135.461 us; speedup vs baseline: 1.1557x; 1.1557x over previous
//
#include <hip/hip_runtime.h>

#define BB 8
#define C 64
#define HW 4096

typedef __attribute__((ext_vector_type(8))) __bf16 bf16x8;
typedef __attribute__((ext_vector_type(16))) float f32x16;
typedef unsigned int uint;
typedef unsigned short ushort;

__device__ __forceinline__ ushort bfb(float f) {
  return __builtin_bit_cast(ushort, (__bf16)f);
}
__device__ __forceinline__ uint pk2(float a, float b) {
  return (uint)bfb(a) | ((uint)bfb(b) << 16);
}
__device__ __forceinline__ uint cvtpk(float a, float b) {
  uint r;
  asm("v_cvt_pk_bf16_f32 %0, %1, %2" : "=v"(r) : "v"(a), "v"(b));
  return r;
}
__device__ __forceinline__ f32x16 mfma_bf16(bf16x8 a, bf16x8 b, f32x16 c) {
  return __builtin_amdgcn_mfma_f32_32x32x16_bf16(a, b, c, 0, 0, 0);
}

// ---------------- fold: build wall A/B fragments for {q*log2e, k, wvp} ----------------
__global__ __launch_bounds__(64) void fold_kernel(const float* __restrict__ w_bn,
                                                  const float* __restrict__ w_q,
                                                  const float* __restrict__ w_k,
                                                  const float* __restrict__ w_v,
                                                  char* __restrict__ wall) {
  const int slot = blockIdx.x;         // ot*4 + kc
  const int ot = slot >> 2, kc = slot & 3;
  const int l = threadIdx.x, lo5 = l & 31, hi = l >> 5;
  float v[8];
  if (ot == 0) {
#pragma unroll
    for (int j = 0; j < 8; ++j)
      v[j] = 1.44269504088896f * w_q[lo5 * 64 + kc * 16 + hi * 8 + j];
  } else if (ot == 1) {
#pragma unroll
    for (int j = 0; j < 8; ++j) v[j] = w_k[lo5 * 64 + kc * 16 + hi * 8 + j];
  } else {
    int c = (ot - 2) * 32 + lo5;
#pragma unroll
    for (int j = 0; j < 8; ++j) {
      int d = kc * 16 + hi * 8 + j;
      float acc = 0.f;
      for (int e = 0; e < 64; ++e) acc += w_bn[c * 128 + 64 + e] * w_v[e * 64 + d];
      v[j] = acc;
    }
  }
  uint4 w;
  w.x = pk2(v[0], v[1]); w.y = pk2(v[2], v[3]);
  w.z = pk2(v[4], v[5]); w.w = pk2(v[6], v[7]);
  *(uint4*)(wall + slot * 1024 + l * 16) = w;
}

// ---------------- prep: q/k/vp via MFMA, outputs in exact fa fragment layouts ----------------
__global__ __launch_bounds__(256) void prep_kernel(const float* __restrict__ x,
                                                   const char* __restrict__ wall,
                                                   char* __restrict__ qd2,
                                                   char* __restrict__ kd2,
                                                   char* __restrict__ vpd2) {
  const int bx = blockIdx.x;
  const int b = bx >> 5, nt2 = bx & 31;
  const int t = threadIdx.x;
  const int wv = t >> 6, l = t & 63, lo5 = l & 31, hi = l >> 5;
  const int chunk = nt2 * 4 + wv;        // 0..127, 32-wide n chunk
  const int n0 = chunk * 32;
  const int tt = chunk >> 1;
  const int n = n0 + lo5;
  const float* xb = x + (size_t)b * C * HW;

  f32x16 fz;
#pragma unroll
  for (int r = 0; r < 16; ++r) fz[r] = 0.f;

  bf16x8 xf[4];
#pragma unroll
  for (int kc = 0; kc < 4; ++kc) {
    float xv[8];
#pragma unroll
    for (int j = 0; j < 8; ++j)
      xv[j] = xb[(size_t)(kc * 16 + hi * 8 + j) * HW + n];
    uint4 u;
    u.x = cvtpk(xv[0], xv[1]); u.y = cvtpk(xv[2], xv[3]);
    u.z = cvtpk(xv[4], xv[5]); u.w = cvtpk(xv[6], xv[7]);
    xf[kc] = __builtin_bit_cast(bf16x8, u);
  }

#pragma unroll
  for (int ot = 0; ot < 4; ++ot) {
    f32x16 acc = fz;
#pragma unroll
    for (int kc = 0; kc < 4; ++kc) {
      bf16x8 wf = *(const bf16x8*)(wall + ((ot << 2) | kc) * 1024 + l * 16);
      acc = (ot < 2) ? mfma_bf16(wf, xf[kc], acc)    // D[col=n][row=out]
                     : mfma_bf16(xf[kc], wf, acc);   // D[col=c][row=m]
    }
    // extract pairs: wlo = pair from hi=0 lane (row offset +0), whi = from hi=1 (+4)
    uint wlo[8], whi[8];
#pragma unroll
    for (int i2 = 0; i2 < 8; ++i2) {
      uint w = cvtpk(acc[2 * i2], acc[2 * i2 + 1]);
      uint p = __shfl_xor(w, 32);
      wlo[i2] = hi ? p : w;
      whi[i2] = hi ? w : p;
    }
    uint4 u40, u41;
    u40.x = hi ? wlo[4] : wlo[0];
    u40.y = hi ? wlo[5] : wlo[1];
    u40.z = hi ? whi[4] : whi[0];
    u40.w = hi ? whi[5] : whi[1];
    u41.x = hi ? wlo[6] : wlo[2];
    u41.y = hi ? wlo[7] : wlo[3];
    u41.z = hi ? whi[6] : whi[2];
    u41.w = hi ? whi[7] : whi[3];
    const int e0 = hi * 2;
    if (ot == 0) {
      char* p = qd2 + ((size_t)b * HW + n) * 64;
      *(uint4*)(p + e0 * 16) = u40;
      *(uint4*)(p + (e0 + 1) * 16) = u41;
    } else if (ot == 1) {
      char* p = kd2 + ((size_t)(b * 64 + tt)) * 4096 + (chunk & 1) * 2048 + (n & 31) * 16;
      *(uint4*)(p + e0 * 512) = u40;
      *(uint4*)(p + (e0 + 1) * 512) = u41;
    } else {
      int c = ((ot - 2) << 5) + lo5;
      int oct0 = (chunk & 1) * 4;
      char* p = vpd2 + ((size_t)(b * 64 + tt)) * 8192 + (c >> 5) * 4096 + (c & 31) * 16;
      *(uint4*)(p + (oct0 + e0) * 512) = u40;
      *(uint4*)(p + (oct0 + e0 + 1) * 512) = u41;
    }
  }
}

// ---------------- gram: per-wave partial G = X X^T, split-x (h+l) bf16 MFMA ----------------
__global__ __launch_bounds__(128) void gram_kernel(const float* __restrict__ x,
                                                   float* __restrict__ Gp) {
  const int bx = blockIdx.x;
  const int b = bx >> 5, ch = bx & 31;
  const int t = threadIdx.x;
  const int wv = t >> 6, l = t & 63, lo5 = l & 31, hi = l >> 5;
  const int n0 = ch * 128 + wv * 64;
  const float* xb = x + (size_t)b * C * HW;
  f32x16 fz;
#pragma unroll
  for (int r = 0; r < 16; ++r) fz[r] = 0.f;
  f32x16 a00 = fz, a01 = fz, a10 = fz, a11 = fz;
#pragma unroll 1
  for (int kc = 0; kc < 4; ++kc) {
    int nb = n0 + kc * 16 + hi * 8;
    const float4* p0 = (const float4*)(xb + (size_t)lo5 * HW + nb);
    const float4* p1 = (const float4*)(xb + (size_t)(32 + lo5) * HW + nb);
    float v0[8], v1[8];
    {
      float4 a = p0[0], bq = p0[1];
      v0[0] = a.x; v0[1] = a.y; v0[2] = a.z; v0[3] = a.w;
      v0[4] = bq.x; v0[5] = bq.y; v0[6] = bq.z; v0[7] = bq.w;
      float4 c = p1[0], d = p1[1];
      v1[0] = c.x; v1[1] = c.y; v1[2] = c.z; v1[3] = c.w;
      v1[4] = d.x; v1[5] = d.y; v1[6] = d.z; v1[7] = d.w;
    }
    uint4 uh0, ul0, uh1, ul1;
    {
      float h[8], e[8];
#pragma unroll
      for (int j = 0; j < 8; ++j) { h[j] = (float)(__bf16)v0[j]; e[j] = v0[j] - h[j]; }
      uh0.x = pk2(h[0], h[1]); uh0.y = pk2(h[2], h[3]); uh0.z = pk2(h[4], h[5]); uh0.w = pk2(h[6], h[7]);
      ul0.x = cvtpk(e[0], e[1]); ul0.y = cvtpk(e[2], e[3]); ul0.z = cvtpk(e[4], e[5]); ul0.w = cvtpk(e[6], e[7]);
#pragma unroll
      for (int j = 0; j < 8; ++j) { h[j] = (float)(__bf16)v1[j]; e[j] = v1[j] - h[j]; }
      uh1.x = pk2(h[0], h[1]); uh1.y = pk2(h[2], h[3]); uh1.z = pk2(h[4], h[5]); uh1.w = pk2(h[6], h[7]);
      ul1.x = cvtpk(e[0], e[1]); ul1.y = cvtpk(e[2], e[3]); ul1.z = cvtpk(e[4], e[5]); ul1.w = cvtpk(e[6], e[7]);
    }
    bf16x8 f0h = __builtin_bit_cast(bf16x8, uh0);
    bf16x8 f0l = __builtin_bit_cast(bf16x8, ul0);
    bf16x8 f1h = __builtin_bit_cast(bf16x8, uh1);
    bf16x8 f1l = __builtin_bit_cast(bf16x8, ul1);
    a00 = mfma_bf16(f0h, f0h, a00); a00 = mfma_bf16(f0h, f0l, a00); a00 = mfma_bf16(f0l, f0h, a00);
    a01 = mfma_bf16(f0h, f1h, a01); a01 = mfma_bf16(f0h, f1l, a01); a01 = mfma_bf16(f0l, f1h, a01);
    a10 = mfma_bf16(f1h, f0h, a10); a10 = mfma_bf16(f1h, f0l, a10); a10 = mfma_bf16(f1l, f0h, a10);
    a11 = mfma_bf16(f1h, f1h, a11); a11 = mfma_bf16(f1h, f1l, a11); a11 = mfma_bf16(f1l, f1h, a11);
  }
  float* g = Gp + (size_t)(bx * 2 + wv) * 4096;
#pragma unroll
  for (int r = 0; r < 16; ++r) {
    int row = (r & 3) + 8 * (r >> 2) + 4 * hi;
    g[row * 64 + lo5] = a00[r];
    g[row * 64 + 32 + lo5] = a01[r];
    g[(32 + row) * 64 + lo5] = a10[r];
    g[(32 + row) * 64 + 32 + lo5] = a11[r];
  }
}

// ---------------- CAM (1024 threads): reduce G, E = Wc G Wc^T, softmax, M1 ([d][o]) ----------------
__global__ __launch_bounds__(1024) void cam_m1_kernel(const float* __restrict__ Gp,
                                                      const float* __restrict__ w_cam,
                                                      const float* __restrict__ w_bn,
                                                      float* __restrict__ m1) {
  __shared__ float gs[4096];
  __shared__ float ts[4096];
  __shared__ float wcs[4096];
  __shared__ float wts[4096];
  const int b = blockIdx.x, t = threadIdx.x;
#pragma unroll
  for (int i = 0; i < 4; ++i) {
    int idx = t + i * 1024;
    float s = 0.f;
    for (int s32 = 0; s32 < 64; ++s32)
      s += Gp[(size_t)(b * 64 + s32) * 4096 + idx];
    gs[idx] = s;
  }
  ((float4*)wcs)[t] = ((const float4*)w_cam)[t];
  __syncthreads();
#pragma unroll
  for (int i = 0; i < 4; ++i) {
    int idx = t + i * 1024;
    int r = idx >> 6, d = idx & 63;
    wts[d * 64 + r] = wcs[r * 64 + d];
  }
  __syncthreads();
  const int lane = t & 63, rg = (t >> 6) * 4;
  float acc[4] = {0.f, 0.f, 0.f, 0.f};
  for (int c = 0; c < 64; ++c) {
    float g = gs[c * 64 + lane];
#pragma unroll
    for (int r = 0; r < 4; ++r) acc[r] += wcs[(rg + r) * 64 + c] * g;
  }
#pragma unroll
  for (int r = 0; r < 4; ++r) ts[(rg + r) * 64 + lane] = acc[r];
  __syncthreads();
#pragma unroll
  for (int r = 0; r < 4; ++r) acc[r] = 0.f;
  for (int d = 0; d < 64; ++d) {
    float w = wts[d * 64 + lane];
#pragma unroll
    for (int r = 0; r < 4; ++r) acc[r] += ts[(rg + r) * 64 + d] * w;
  }
  __syncthreads();
#pragma unroll
  for (int r = 0; r < 4; ++r) gs[(rg + r) * 64 + lane] = acc[r];
  __syncthreads();
  {
    // softmax: 16 lanes per row, 4 cols each
    int row = t >> 4, c0 = (t & 15) * 4;
    float v0 = gs[row * 64 + c0], v1 = gs[row * 64 + c0 + 1];
    float v2 = gs[row * 64 + c0 + 2], v3 = gs[row * 64 + c0 + 3];
    float mx = fmaxf(fmaxf(v0, v1), fmaxf(v2, v3));
#pragma unroll
    for (int o = 1; o < 16; o <<= 1) mx = fmaxf(mx, __shfl_xor(mx, o));
    float e0 = __expf(v0 - mx), e1 = __expf(v1 - mx);
    float e2 = __expf(v2 - mx), e3 = __expf(v3 - mx);
    float s = e0 + e1 + e2 + e3;
#pragma unroll
    for (int o = 1; o < 16; o <<= 1) s += __shfl_xor(s, o);
    float inv = 1.f / s;
    wcs[row * 64 + c0] = e0 * inv;
    wcs[row * 64 + c0 + 1] = e1 * inv;
    wcs[row * 64 + c0 + 2] = e2 * inv;
    wcs[row * 64 + c0 + 3] = e3 * inv;
  }
#pragma unroll
  for (int i = 0; i < 4; ++i) {
    int idx = t + i * 1024;
    int o = idx & 63, r = idx >> 6;
    wts[r * 64 + o] = w_bn[o * 128 + r];
  }
  __syncthreads();
  float a2[4] = {0.f, 0.f, 0.f, 0.f};
  for (int r = 0; r < 64; ++r) {
    float wv = wts[r * 64 + lane];
#pragma unroll
    for (int dd = 0; dd < 4; ++dd) a2[dd] += wv * wcs[r * 64 + rg + dd];
  }
  float* mb = m1 + (size_t)b * 4096;
#pragma unroll
  for (int dd = 0; dd < 4; ++dd) mb[(rg + dd) * 64 + lane] = a2[dd];
}

// ---------------- SAM flash attention: direct global->reg fragments (L2/L1-resident K/V),
// no LDS, no barriers; K register-double-buffered ----------------
__global__ __launch_bounds__(256) void fa_kernel(const char* __restrict__ qd2,
                                                 const char* __restrict__ kd2,
                                                 const char* __restrict__ vpd2,
                                                 char* __restrict__ op,
                                                 float* __restrict__ lp) {
  const int t = threadIdx.x;
  const int l = t & 63, lo5 = l & 31, hi = l >> 5;
  const int wv = t >> 6;
  const int bx = blockIdx.x;
  const int g = (bx & 7) | ((bx >> 8) << 3);   // XCD-aligned: group g lives on XCD g&7
  const int qt = (bx >> 3) & 31;
  const int b = g >> 2, kvs = g & 3;
  const int nq = qt * 128 + wv * 32 + lo5;

  const char* qb = qd2 + ((size_t)b * HW + nq) * 64;
  bf16x8 qf0 = *(const bf16x8*)(qb + hi * 16);
  bf16x8 qf1 = *(const bf16x8*)(qb + 32 + hi * 16);

  f32x16 fz;
#pragma unroll
  for (int r = 0; r < 16; ++r) fz[r] = 0.f;
  f32x16 o0 = fz, o1 = fz;
  float lrun = 0.f;

  const char* kbase = kd2 + ((size_t)(b * 64 + kvs * 16)) * 4096 + l * 16;
  const char* vbase = vpd2 + ((size_t)(b * 64 + kvs * 16)) * 8192 + l * 16;

  bf16x8 kf0 = *(const bf16x8*)(kbase);
  bf16x8 kf1 = *(const bf16x8*)(kbase + 1024);
  bf16x8 kf2 = *(const bf16x8*)(kbase + 2048);
  bf16x8 kf3 = *(const bf16x8*)(kbase + 3072);

#pragma unroll 1
  for (int i = 0; i < 16; ++i) {
    bf16x8 kn0, kn1, kn2, kn3;
    if (i < 15) {
      const char* kn = kbase + (size_t)(i + 1) * 4096;
      kn0 = *(const bf16x8*)(kn);
      kn1 = *(const bf16x8*)(kn + 1024);
      kn2 = *(const bf16x8*)(kn + 2048);
      kn3 = *(const bf16x8*)(kn + 3072);
    }
    const char* vb = vbase + (size_t)i * 8192;
    bf16x8 vfa[4], vfb[4];
#pragma unroll
    for (int ks = 0; ks < 4; ++ks) {
      vfa[ks] = *(const bf16x8*)(vb + ks * 1024);
      vfb[ks] = *(const bf16x8*)(vb + 4096 + ks * 1024);
    }
    f32x16 s0 = mfma_bf16(kf0, qf0, fz);
    s0 = mfma_bf16(kf1, qf1, s0);
    f32x16 s1 = mfma_bf16(kf2, qf0, fz);
    s1 = mfma_bf16(kf3, qf1, s1);
    float ps = 0.f;
#pragma unroll
    for (int r = 0; r < 16; ++r) {
      s0[r] = __builtin_amdgcn_exp2f(s0[r]);
      ps += s0[r];
    }
#pragma unroll
    for (int r = 0; r < 16; ++r) {
      s1[r] = __builtin_amdgcn_exp2f(s1[r]);
      ps += s1[r];
    }
    lrun += ps;                    // lane-local; cross-half merge once at end
#pragma unroll
    for (int ks = 0; ks < 4; ++ks) {
      const f32x16& pm = (ks < 2) ? s0 : s1;
      const int rb = (ks & 1) * 8;
      uint w0 = cvtpk(pm[rb + 0], pm[rb + 1]);
      uint w1 = cvtpk(pm[rb + 2], pm[rb + 3]);
      uint w2 = cvtpk(pm[rb + 4], pm[rb + 5]);
      uint w3 = cvtpk(pm[rb + 6], pm[rb + 7]);
      uint x0 = __shfl_xor(w0, 32);
      uint x1 = __shfl_xor(w1, 32);
      uint x2 = __shfl_xor(w2, 32);
      uint x3 = __shfl_xor(w3, 32);
      uint4 fw;
      fw.x = hi ? x2 : w0;
      fw.y = hi ? x3 : w1;
      fw.z = hi ? w2 : x0;
      fw.w = hi ? w3 : x1;
      bf16x8 pf = __builtin_bit_cast(bf16x8, fw);
      o0 = mfma_bf16(vfa[ks], pf, o0);
      o1 = mfma_bf16(vfb[ks], pf, o1);
    }
    kf0 = kn0; kf1 = kn1; kf2 = kn2; kf3 = kn3;
  }
  lrun += __shfl_xor(lrun, 32);

  ushort* opu = (ushort*)op;
  const size_t obase = ((size_t)(b * 64) * 4 + kvs) * HW + nq;
#pragma unroll
  for (int r = 0; r < 16; ++r) {
    int c0 = (r & 3) + 8 * (r >> 2) + 4 * hi;
    opu[obase + (size_t)c0 * 4 * HW] = bfb(o0[r]);
    opu[obase + (size_t)(c0 + 32) * 4 * HW] = bfb(o1[r]);
  }
  if (hi == 0) lp[(size_t)(kvs * 8 + b) * HW + nq] = lrun;
}

// ---------------- epilogue: out = x + M1@x + merge(op)/merge(l) ----------------
__global__ __launch_bounds__(256) void final_kernel(const float* __restrict__ x,
                                                    const float* __restrict__ m1,
                                                    const char* __restrict__ op,
                                                    const float* __restrict__ lp,
                                                    float* __restrict__ outp) {
  __shared__ __align__(16) float xt[4096];
  __shared__ __align__(16) float ms[4096];
  const int b = blockIdx.y, tt = blockIdx.x, t = threadIdx.x;
  const float4* xg = (const float4*)(x + (size_t)b * C * HW);
  float4* xt4 = (float4*)xt;
#pragma unroll
  for (int i = 0; i < 4; ++i) {
    int idx = t + i * 256;
    int c = idx >> 4, ng = idx & 15;
    xt4[c * 16 + (ng ^ (c & 15))] = xg[c * 1024 + tt * 16 + ng];
  }
  float4* ms4 = (float4*)ms;
  const float4* mg = (const float4*)(m1 + (size_t)b * 4096);
#pragma unroll
  for (int i = 0; i < 4; ++i) ms4[t + i * 256] = mg[t + i * 256];
  __syncthreads();
  const int n = t & 63, sub = t >> 6;
  const int gn = tt * 64 + n;
  float xr[64];
#pragma unroll
  for (int c = 0; c < 64; ++c)
    xr[c] = xt[c * 64 + (((n >> 2) ^ (c & 15)) << 2) + (n & 3)];
  float lsum = 0.f;
#pragma unroll
  for (int kvs = 0; kvs < 4; ++kvs) lsum += lp[(size_t)(kvs * 8 + b) * HW + gn];
  float linv = 1.f / lsum;
  const ushort* opu = (const ushort*)op;
  float acc[16];
#pragma unroll
  for (int ci = 0; ci < 16; ++ci) {
    int c = sub * 16 + ci;
    float osum = 0.f;
#pragma unroll
    for (int kvs = 0; kvs < 4; ++kvs) {
      ushort u = opu[((size_t)(b * 64 + c) * 4 + kvs) * HW + gn];
      osum += __builtin_bit_cast(float, (uint)u << 16);
    }
    acc[ci] = xr[c] + osum * linv;
  }
  for (int d = 0; d < 64; ++d) {
    float xv = xr[d];
    const float4* mr = (const float4*)(ms + d * 64 + sub * 16);
#pragma unroll
    for (int c4 = 0; c4 < 4; ++c4) {
      float4 mv = mr[c4];
      acc[c4 * 4 + 0] += mv.x * xv;
      acc[c4 * 4 + 1] += mv.y * xv;
      acc[c4 * 4 + 2] += mv.z * xv;
      acc[c4 * 4 + 3] += mv.w * xv;
    }
  }
  float* ob = outp + (size_t)b * C * HW + gn;
#pragma unroll
  for (int ci = 0; ci < 16; ++ci)
    ob[(size_t)(sub * 16 + ci) * HW] = acc[ci];
}

extern "C" void kernel_launch(void* const* d_in, const int* in_sizes, int n_in,
                              void* d_out, int out_size, void* d_ws, size_t ws_size,
                              hipStream_t stream) {
  const float* x     = (const float*)d_in[0];
  const float* w_cam = (const float*)d_in[1];
  const float* w_q   = (const float*)d_in[2];
  const float* w_k   = (const float*)d_in[3];
  const float* w_v   = (const float*)d_in[4];
  const float* w_bn  = (const float*)d_in[5];
  float* out = (float*)d_out;
  char* wsb = (char*)d_ws;

  // workspace layout (bytes)
  char*  wall = wsb;                               // 16 KB  wall fragments
  float* m1   = (float*)(wsb + 16384);             // 128 KB
  char*  qd2  = wsb + 147456;                      // 2 MB
  char*  kd2  = qd2 + 2097152;                     // 2 MB
  char*  vpd2 = kd2 + 2097152;                     // 4 MB
  float* lp   = (float*)(vpd2 + 4194304);          // 512 KB
  char*  un   = (char*)lp + 524288;                // 16 MB union: Gp (8MB) then op (16MB)
  float* Gp   = (float*)un;
  char*  op   = un;

  fold_kernel<<<16, 64, 0, stream>>>(w_bn, w_q, w_k, w_v, wall);
  prep_kernel<<<256, 256, 0, stream>>>(x, wall, qd2, kd2, vpd2);
  gram_kernel<<<256, 128, 0, stream>>>(x, Gp);
  cam_m1_kernel<<<8, 1024, 0, stream>>>(Gp, w_cam, w_bn, m1);
  fa_kernel<<<1024, 256, 0, stream>>>(qd2, kd2, vpd2, op, lp);
  final_kernel<<<dim3(64, BB), 256, 0, stream>>>(x, m1, op, lp, out);
}

// Round 10
// 104.369 us; speedup vs baseline: 1.5000x; 1.2979x over previous
//
#include <hip/hip_runtime.h>

#define BB 8
#define C 64
#define HW 4096

typedef __attribute__((ext_vector_type(8))) __bf16 bf16x8;
typedef __attribute__((ext_vector_type(16))) float f32x16;
typedef unsigned int uint;
typedef unsigned short ushort;

__device__ __forceinline__ ushort bfb(float f) {
  return __builtin_bit_cast(ushort, (__bf16)f);
}
__device__ __forceinline__ uint pk2(float a, float b) {
  return (uint)bfb(a) | ((uint)bfb(b) << 16);
}
__device__ __forceinline__ uint cvtpk(float a, float b) {
  uint r;
  asm("v_cvt_pk_bf16_f32 %0, %1, %2" : "=v"(r) : "v"(a), "v"(b));
  return r;
}
__device__ __forceinline__ f32x16 mfma_bf16(bf16x8 a, bf16x8 b, f32x16 c) {
  return __builtin_amdgcn_mfma_f32_32x32x16_bf16(a, b, c, 0, 0, 0);
}

// ---------------- K1: [fold | gram] ----------------
// fold: build wall A/B fragments for {q*log2e, k, wvp}; 16 slots, 2 per block.
// gram: per-wave partial G = X X^T, split-x (h+l) bf16 MFMA, atomicAdd into G.
__global__ __launch_bounds__(128) void gram_fold_kernel(const float* __restrict__ x,
                                                        float* __restrict__ G,
                                                        const float* __restrict__ w_bn,
                                                        const float* __restrict__ w_q,
                                                        const float* __restrict__ w_k,
                                                        const float* __restrict__ w_v,
                                                        char* __restrict__ wall) {
  const int bxx = blockIdx.x;
  const int t = threadIdx.x;
  if (bxx < 8) {
    // ---- fold ----
    const int slot = bxx * 2 + (t >> 6);   // ot*4 + kc
    const int ot = slot >> 2, kc = slot & 3;
    const int l = t & 63, lo5 = l & 31, hi = l >> 5;
    float v[8];
    if (ot == 0) {
#pragma unroll
      for (int j = 0; j < 8; ++j)
        v[j] = 1.44269504088896f * w_q[lo5 * 64 + kc * 16 + hi * 8 + j];
    } else if (ot == 1) {
#pragma unroll
      for (int j = 0; j < 8; ++j) v[j] = w_k[lo5 * 64 + kc * 16 + hi * 8 + j];
    } else {
      int c = (ot - 2) * 32 + lo5;
#pragma unroll
      for (int j = 0; j < 8; ++j) {
        int d = kc * 16 + hi * 8 + j;
        float acc = 0.f;
        for (int e = 0; e < 64; ++e) acc += w_bn[c * 128 + 64 + e] * w_v[e * 64 + d];
        v[j] = acc;
      }
    }
    uint4 w;
    w.x = pk2(v[0], v[1]); w.y = pk2(v[2], v[3]);
    w.z = pk2(v[4], v[5]); w.w = pk2(v[6], v[7]);
    *(uint4*)(wall + slot * 1024 + l * 16) = w;
    return;
  }
  // ---- gram ----
  const int bx = bxx - 8;
  const int b = bx >> 5, ch = bx & 31;
  const int wv = t >> 6, l = t & 63, lo5 = l & 31, hi = l >> 5;
  const int n0 = ch * 128 + wv * 64;
  const float* xb = x + (size_t)b * C * HW;
  f32x16 fz;
#pragma unroll
  for (int r = 0; r < 16; ++r) fz[r] = 0.f;
  f32x16 a00 = fz, a01 = fz, a10 = fz, a11 = fz;
#pragma unroll 1
  for (int kc = 0; kc < 4; ++kc) {
    int nb = n0 + kc * 16 + hi * 8;
    const float4* p0 = (const float4*)(xb + (size_t)lo5 * HW + nb);
    const float4* p1 = (const float4*)(xb + (size_t)(32 + lo5) * HW + nb);
    float v0[8], v1[8];
    {
      float4 a = p0[0], bq = p0[1];
      v0[0] = a.x; v0[1] = a.y; v0[2] = a.z; v0[3] = a.w;
      v0[4] = bq.x; v0[5] = bq.y; v0[6] = bq.z; v0[7] = bq.w;
      float4 c = p1[0], d = p1[1];
      v1[0] = c.x; v1[1] = c.y; v1[2] = c.z; v1[3] = c.w;
      v1[4] = d.x; v1[5] = d.y; v1[6] = d.z; v1[7] = d.w;
    }
    uint4 uh0, ul0, uh1, ul1;
    {
      float h[8], e[8];
#pragma unroll
      for (int j = 0; j < 8; ++j) { h[j] = (float)(__bf16)v0[j]; e[j] = v0[j] - h[j]; }
      uh0.x = pk2(h[0], h[1]); uh0.y = pk2(h[2], h[3]); uh0.z = pk2(h[4], h[5]); uh0.w = pk2(h[6], h[7]);
      ul0.x = cvtpk(e[0], e[1]); ul0.y = cvtpk(e[2], e[3]); ul0.z = cvtpk(e[4], e[5]); ul0.w = cvtpk(e[6], e[7]);
#pragma unroll
      for (int j = 0; j < 8; ++j) { h[j] = (float)(__bf16)v1[j]; e[j] = v1[j] - h[j]; }
      uh1.x = pk2(h[0], h[1]); uh1.y = pk2(h[2], h[3]); uh1.z = pk2(h[4], h[5]); uh1.w = pk2(h[6], h[7]);
      ul1.x = cvtpk(e[0], e[1]); ul1.y = cvtpk(e[2], e[3]); ul1.z = cvtpk(e[4], e[5]); ul1.w = cvtpk(e[6], e[7]);
    }
    bf16x8 f0h = __builtin_bit_cast(bf16x8, uh0);
    bf16x8 f0l = __builtin_bit_cast(bf16x8, ul0);
    bf16x8 f1h = __builtin_bit_cast(bf16x8, uh1);
    bf16x8 f1l = __builtin_bit_cast(bf16x8, ul1);
    a00 = mfma_bf16(f0h, f0h, a00); a00 = mfma_bf16(f0h, f0l, a00); a00 = mfma_bf16(f0l, f0h, a00);
    a01 = mfma_bf16(f0h, f1h, a01); a01 = mfma_bf16(f0h, f1l, a01); a01 = mfma_bf16(f0l, f1h, a01);
    a10 = mfma_bf16(f1h, f0h, a10); a10 = mfma_bf16(f1h, f0l, a10); a10 = mfma_bf16(f1l, f0h, a10);
    a11 = mfma_bf16(f1h, f1h, a11); a11 = mfma_bf16(f1h, f1l, a11); a11 = mfma_bf16(f1l, f1h, a11);
  }
  float* g = G + (size_t)b * 4096;
#pragma unroll
  for (int r = 0; r < 16; ++r) {
    int row = (r & 3) + 8 * (r >> 2) + 4 * hi;
    atomicAdd(&g[row * 64 + lo5], a00[r]);
    atomicAdd(&g[row * 64 + 32 + lo5], a01[r]);
    atomicAdd(&g[(32 + row) * 64 + lo5], a10[r]);
    atomicAdd(&g[(32 + row) * 64 + 32 + lo5], a11[r]);
  }
}

// ---------------- prep: q/k/vp via MFMA, outputs in exact fa fragment layouts ----------------
__global__ __launch_bounds__(256) void prep_kernel(const float* __restrict__ x,
                                                   const char* __restrict__ wall,
                                                   char* __restrict__ qd2,
                                                   char* __restrict__ kd2,
                                                   char* __restrict__ vpd2) {
  const int bx = blockIdx.x;
  const int b = bx >> 5, nt2 = bx & 31;
  const int t = threadIdx.x;
  const int wv = t >> 6, l = t & 63, lo5 = l & 31, hi = l >> 5;
  const int chunk = nt2 * 4 + wv;        // 0..127, 32-wide n chunk
  const int n0 = chunk * 32;
  const int tt = chunk >> 1;
  const int n = n0 + lo5;
  const float* xb = x + (size_t)b * C * HW;

  f32x16 fz;
#pragma unroll
  for (int r = 0; r < 16; ++r) fz[r] = 0.f;

  bf16x8 xf[4];
#pragma unroll
  for (int kc = 0; kc < 4; ++kc) {
    float xv[8];
#pragma unroll
    for (int j = 0; j < 8; ++j)
      xv[j] = xb[(size_t)(kc * 16 + hi * 8 + j) * HW + n];
    uint4 u;
    u.x = cvtpk(xv[0], xv[1]); u.y = cvtpk(xv[2], xv[3]);
    u.z = cvtpk(xv[4], xv[5]); u.w = cvtpk(xv[6], xv[7]);
    xf[kc] = __builtin_bit_cast(bf16x8, u);
  }

#pragma unroll
  for (int ot = 0; ot < 4; ++ot) {
    f32x16 acc = fz;
#pragma unroll
    for (int kc = 0; kc < 4; ++kc) {
      bf16x8 wf = *(const bf16x8*)(wall + ((ot << 2) | kc) * 1024 + l * 16);
      acc = (ot < 2) ? mfma_bf16(wf, xf[kc], acc)    // D[col=n][row=out]
                     : mfma_bf16(xf[kc], wf, acc);   // D[col=c][row=m]
    }
    // extract pairs: wlo = pair from hi=0 lane (row offset +0), whi = from hi=1 (+4)
    uint wlo[8], whi[8];
#pragma unroll
    for (int i2 = 0; i2 < 8; ++i2) {
      uint w = cvtpk(acc[2 * i2], acc[2 * i2 + 1]);
      uint p = __shfl_xor(w, 32);
      wlo[i2] = hi ? p : w;
      whi[i2] = hi ? w : p;
    }
    uint4 u40, u41;
    u40.x = hi ? wlo[4] : wlo[0];
    u40.y = hi ? wlo[5] : wlo[1];
    u40.z = hi ? whi[4] : whi[0];
    u40.w = hi ? whi[5] : whi[1];
    u41.x = hi ? wlo[6] : wlo[2];
    u41.y = hi ? wlo[7] : wlo[3];
    u41.z = hi ? whi[6] : whi[2];
    u41.w = hi ? whi[7] : whi[3];
    const int e0 = hi * 2;
    if (ot == 0) {
      char* p = qd2 + ((size_t)b * HW + n) * 64;
      *(uint4*)(p + e0 * 16) = u40;
      *(uint4*)(p + (e0 + 1) * 16) = u41;
    } else if (ot == 1) {
      char* p = kd2 + ((size_t)(b * 64 + tt)) * 4096 + (chunk & 1) * 2048 + (n & 31) * 16;
      *(uint4*)(p + e0 * 512) = u40;
      *(uint4*)(p + (e0 + 1) * 512) = u41;
    } else {
      int c = ((ot - 2) << 5) + lo5;
      int oct0 = (chunk & 1) * 4;
      char* p = vpd2 + ((size_t)(b * 64 + tt)) * 8192 + (c >> 5) * 4096 + (c & 31) * 16;
      *(uint4*)(p + (oct0 + e0) * 512) = u40;
      *(uint4*)(p + (oct0 + e0 + 1) * 512) = u41;
    }
  }
}

// ---------------- cam body (256 threads, 16 KB LDS): E = Wc G Wc^T, softmax, M1 ([d][o]) ----------------
__device__ __forceinline__ void cam_body(const float* __restrict__ G,
                                         const float* __restrict__ w_cam,
                                         const float* __restrict__ w_bn,
                                         float* __restrict__ m1,
                                         int b, float* buf) {
  const int t = threadIdx.x;
  // phase 0: load G[b]
#pragma unroll
  for (int i = 0; i < 16; ++i) {
    int idx = t + i * 256;
    buf[idx] = G[(size_t)b * 4096 + idx];
  }
  __syncthreads();
  const int lane = t & 63, rg = (t >> 6) * 16;
  // phase 1: T1 = Wc @ G -> regs (row rg+r, col lane)
  float acc[16];
#pragma unroll
  for (int r = 0; r < 16; ++r) acc[r] = 0.f;
  for (int c = 0; c < 64; ++c) {
    float g = buf[c * 64 + lane];
#pragma unroll
    for (int r = 0; r < 16; ++r) acc[r] += w_cam[(rg + r) * 64 + c] * g;
  }
  __syncthreads();
#pragma unroll
  for (int r = 0; r < 16; ++r) buf[(rg + r) * 64 + lane] = acc[r];   // T1
  __syncthreads();
  // phase 2: E = T1 @ Wc^T
#pragma unroll
  for (int r = 0; r < 16; ++r) acc[r] = 0.f;
  for (int d = 0; d < 64; ++d) {
    float wl = w_cam[lane * 64 + d];
#pragma unroll
    for (int r = 0; r < 16; ++r) acc[r] += buf[(rg + r) * 64 + d] * wl;
  }
  __syncthreads();
#pragma unroll
  for (int r = 0; r < 16; ++r) buf[(rg + r) * 64 + lane] = acc[r];   // E
  __syncthreads();
  // phase 3: row softmax (4 threads per row, 16 cols each)
  {
    int row = t >> 2, c0 = (t & 3) * 16;
    float v[16];
    float mx = -1e30f;
#pragma unroll
    for (int j = 0; j < 16; ++j) { v[j] = buf[row * 64 + c0 + j]; mx = fmaxf(mx, v[j]); }
    mx = fmaxf(mx, __shfl_xor(mx, 1));
    mx = fmaxf(mx, __shfl_xor(mx, 2));
    float s = 0.f;
#pragma unroll
    for (int j = 0; j < 16; ++j) { v[j] = __expf(v[j] - mx); s += v[j]; }
    s += __shfl_xor(s, 1);
    s += __shfl_xor(s, 2);
    float inv = 1.f / s;
#pragma unroll
    for (int j = 0; j < 16; ++j) buf[row * 64 + c0 + j] = v[j] * inv;  // attn
  }
  __syncthreads();
  // phase 4: M1[d][o] = sum_r w_bn1[o][r] * attn[r][d]
  float a2[16];
#pragma unroll
  for (int dd = 0; dd < 16; ++dd) a2[dd] = 0.f;
  for (int r = 0; r < 64; ++r) {
    float wv = w_bn[lane * 128 + r];
#pragma unroll
    for (int dd = 0; dd < 16; ++dd) a2[dd] += wv * buf[r * 64 + rg + dd];
  }
  float* mb = m1 + (size_t)b * 4096;
#pragma unroll
  for (int dd = 0; dd < 16; ++dd) mb[(rg + dd) * 64 + lane] = a2[dd];
}

// ---------------- K3: [cam | fa]; fa = direct global->reg fragments, no LDS/barriers ----------------
__global__ __launch_bounds__(256) void fa_cam_kernel(const char* __restrict__ qd2,
                                                     const char* __restrict__ kd2,
                                                     const char* __restrict__ vpd2,
                                                     char* __restrict__ op,
                                                     float* __restrict__ lp,
                                                     const float* __restrict__ G,
                                                     const float* __restrict__ w_cam,
                                                     const float* __restrict__ w_bn,
                                                     float* __restrict__ m1) {
  __shared__ float buf[4096];
  const int bxx = blockIdx.x;
  if (bxx < 8) {
    cam_body(G, w_cam, w_bn, m1, bxx, buf);
    return;
  }
  const int bx = bxx - 8;
  const int t = threadIdx.x;
  const int l = t & 63, lo5 = l & 31, hi = l >> 5;
  const int wv = t >> 6;
  const int g = (bx & 7) | ((bx >> 8) << 3);
  const int qt = (bx >> 3) & 31;
  const int b = g >> 2, kvs = g & 3;
  const int nq = qt * 128 + wv * 32 + lo5;

  const char* qb = qd2 + ((size_t)b * HW + nq) * 64;
  bf16x8 qf0 = *(const bf16x8*)(qb + hi * 16);
  bf16x8 qf1 = *(const bf16x8*)(qb + 32 + hi * 16);

  f32x16 fz;
#pragma unroll
  for (int r = 0; r < 16; ++r) fz[r] = 0.f;
  f32x16 o0 = fz, o1 = fz;
  float lrun = 0.f;

  const char* kbase = kd2 + ((size_t)(b * 64 + kvs * 16)) * 4096 + l * 16;
  const char* vbase = vpd2 + ((size_t)(b * 64 + kvs * 16)) * 8192 + l * 16;

  bf16x8 kf0 = *(const bf16x8*)(kbase);
  bf16x8 kf1 = *(const bf16x8*)(kbase + 1024);
  bf16x8 kf2 = *(const bf16x8*)(kbase + 2048);
  bf16x8 kf3 = *(const bf16x8*)(kbase + 3072);

#pragma unroll 1
  for (int i = 0; i < 16; ++i) {
    bf16x8 kn0, kn1, kn2, kn3;
    if (i < 15) {
      const char* kn = kbase + (size_t)(i + 1) * 4096;
      kn0 = *(const bf16x8*)(kn);
      kn1 = *(const bf16x8*)(kn + 1024);
      kn2 = *(const bf16x8*)(kn + 2048);
      kn3 = *(const bf16x8*)(kn + 3072);
    }
    const char* vb = vbase + (size_t)i * 8192;
    bf16x8 vfa[4], vfb[4];
#pragma unroll
    for (int ks = 0; ks < 4; ++ks) {
      vfa[ks] = *(const bf16x8*)(vb + ks * 1024);
      vfb[ks] = *(const bf16x8*)(vb + 4096 + ks * 1024);
    }
    f32x16 s0 = mfma_bf16(kf0, qf0, fz);
    s0 = mfma_bf16(kf1, qf1, s0);
    f32x16 s1 = mfma_bf16(kf2, qf0, fz);
    s1 = mfma_bf16(kf3, qf1, s1);
    float ps = 0.f;
#pragma unroll
    for (int r = 0; r < 16; ++r) {
      s0[r] = __builtin_amdgcn_exp2f(s0[r]);
      ps += s0[r];
    }
#pragma unroll
    for (int r = 0; r < 16; ++r) {
      s1[r] = __builtin_amdgcn_exp2f(s1[r]);
      ps += s1[r];
    }
    lrun += ps;                    // lane-local; cross-half merge once at end
#pragma unroll
    for (int ks = 0; ks < 4; ++ks) {
      const f32x16& pm = (ks < 2) ? s0 : s1;
      const int rb = (ks & 1) * 8;
      uint w0 = cvtpk(pm[rb + 0], pm[rb + 1]);
      uint w1 = cvtpk(pm[rb + 2], pm[rb + 3]);
      uint w2 = cvtpk(pm[rb + 4], pm[rb + 5]);
      uint w3 = cvtpk(pm[rb + 6], pm[rb + 7]);
      uint x0 = __shfl_xor(w0, 32);
      uint x1 = __shfl_xor(w1, 32);
      uint x2 = __shfl_xor(w2, 32);
      uint x3 = __shfl_xor(w3, 32);
      uint4 fw;
      fw.x = hi ? x2 : w0;
      fw.y = hi ? x3 : w1;
      fw.z = hi ? w2 : x0;
      fw.w = hi ? w3 : x1;
      bf16x8 pf = __builtin_bit_cast(bf16x8, fw);
      o0 = mfma_bf16(vfa[ks], pf, o0);
      o1 = mfma_bf16(vfb[ks], pf, o1);
    }
    kf0 = kn0; kf1 = kn1; kf2 = kn2; kf3 = kn3;
  }
  lrun += __shfl_xor(lrun, 32);

  ushort* opu = (ushort*)op;
  const size_t obase = ((size_t)(b * 64) * 4 + kvs) * HW + nq;
#pragma unroll
  for (int r = 0; r < 16; ++r) {
    int c0 = (r & 3) + 8 * (r >> 2) + 4 * hi;
    opu[obase + (size_t)c0 * 4 * HW] = bfb(o0[r]);
    opu[obase + (size_t)(c0 + 32) * 4 * HW] = bfb(o1[r]);
  }
  if (hi == 0) lp[(size_t)(kvs * 8 + b) * HW + nq] = lrun;
}

// ---------------- epilogue: out = x + M1@x + merge(op)/merge(l) ----------------
__global__ __launch_bounds__(256) void final_kernel(const float* __restrict__ x,
                                                    const float* __restrict__ m1,
                                                    const char* __restrict__ op,
                                                    const float* __restrict__ lp,
                                                    float* __restrict__ outp) {
  __shared__ __align__(16) float xt[4096];
  __shared__ __align__(16) float ms[4096];
  const int b = blockIdx.y, tt = blockIdx.x, t = threadIdx.x;
  const float4* xg = (const float4*)(x + (size_t)b * C * HW);
  float4* xt4 = (float4*)xt;
#pragma unroll
  for (int i = 0; i < 4; ++i) {
    int idx = t + i * 256;
    int c = idx >> 4, ng = idx & 15;
    xt4[c * 16 + (ng ^ (c & 15))] = xg[c * 1024 + tt * 16 + ng];
  }
  float4* ms4 = (float4*)ms;
  const float4* mg = (const float4*)(m1 + (size_t)b * 4096);
#pragma unroll
  for (int i = 0; i < 4; ++i) ms4[t + i * 256] = mg[t + i * 256];
  __syncthreads();
  const int n = t & 63, sub = t >> 6;
  const int gn = tt * 64 + n;
  float xr[64];
#pragma unroll
  for (int c = 0; c < 64; ++c)
    xr[c] = xt[c * 64 + (((n >> 2) ^ (c & 15)) << 2) + (n & 3)];
  float lsum = 0.f;
#pragma unroll
  for (int kvs = 0; kvs < 4; ++kvs) lsum += lp[(size_t)(kvs * 8 + b) * HW + gn];
  float linv = 1.f / lsum;
  const ushort* opu = (const ushort*)op;
  float acc[16];
#pragma unroll
  for (int ci = 0; ci < 16; ++ci) {
    int c = sub * 16 + ci;
    float osum = 0.f;
#pragma unroll
    for (int kvs = 0; kvs < 4; ++kvs) {
      ushort u = opu[((size_t)(b * 64 + c) * 4 + kvs) * HW + gn];
      osum += __builtin_bit_cast(float, (uint)u << 16);
    }
    acc[ci] = xr[c] + osum * linv;
  }
  for (int d = 0; d < 64; ++d) {
    float xv = xr[d];
    const float4* mr = (const float4*)(ms + d * 64 + sub * 16);
#pragma unroll
    for (int c4 = 0; c4 < 4; ++c4) {
      float4 mv = mr[c4];
      acc[c4 * 4 + 0] += mv.x * xv;
      acc[c4 * 4 + 1] += mv.y * xv;
      acc[c4 * 4 + 2] += mv.z * xv;
      acc[c4 * 4 + 3] += mv.w * xv;
    }
  }
  float* ob = outp + (size_t)b * C * HW + gn;
#pragma unroll
  for (int ci = 0; ci < 16; ++ci)
    ob[(size_t)(sub * 16 + ci) * HW] = acc[ci];
}

extern "C" void kernel_launch(void* const* d_in, const int* in_sizes, int n_in,
                              void* d_out, int out_size, void* d_ws, size_t ws_size,
                              hipStream_t stream) {
  const float* x     = (const float*)d_in[0];
  const float* w_cam = (const float*)d_in[1];
  const float* w_q   = (const float*)d_in[2];
  const float* w_k   = (const float*)d_in[3];
  const float* w_v   = (const float*)d_in[4];
  const float* w_bn  = (const float*)d_in[5];
  float* out = (float*)d_out;
  char* wsb = (char*)d_ws;

  // workspace layout (bytes)  — total ~24.8 MB
  char*  wall = wsb;                               // 16 KB  wall fragments
  float* m1   = (float*)(wsb + 16384);             // 128 KB
  float* G    = (float*)(wsb + 147456);            // 128 KB
  char*  qd2  = wsb + 278528;                      // 2 MB
  char*  kd2  = qd2 + 2097152;                     // 2 MB
  char*  vpd2 = kd2 + 2097152;                     // 4 MB
  float* lp   = (float*)(vpd2 + 4194304);          // 512 KB
  char*  op   = (char*)lp + 524288;                // 16 MB

  hipMemsetAsync(G, 0, (size_t)BB * 4096 * sizeof(float), stream);
  gram_fold_kernel<<<264, 128, 0, stream>>>(x, G, w_bn, w_q, w_k, w_v, wall);
  prep_kernel<<<256, 256, 0, stream>>>(x, wall, qd2, kd2, vpd2);
  fa_cam_kernel<<<1032, 256, 0, stream>>>(qd2, kd2, vpd2, op, lp, G, w_cam, w_bn, m1);
  final_kernel<<<dim3(64, BB), 256, 0, stream>>>(x, m1, op, lp, out);
}